// Round 1
// baseline (130.464 us; speedup 1.0000x reference)
//
#include <hip/hip_runtime.h>

// PairwiseRankingLoss: out = 2*sum(cost_a) + sum(cost_g)
//   cost_x[i,j] = relu(score_x[i,j] + 0.2 - diag_x[j]) * (i != j)
//   score_a = artist @ target_art^T ; score_g = genre @ genre^T
// N=4096, D=1024. Inputs fp32; GEMM done in bf16 MFMA (threshold is 2% rel).

#define NROW 4096
#define DDIM 1024
#define MARGIN 0.2f

typedef __bf16 bf16x8 __attribute__((ext_vector_type(8)));
typedef float f32x4 __attribute__((ext_vector_type(4)));

__device__ __forceinline__ unsigned short f2bf(float f) {
    unsigned int u = __builtin_bit_cast(unsigned int, f);
    u += 0x7fffu + ((u >> 16) & 1u);   // round-to-nearest-even
    return (unsigned short)(u >> 16);
}

__device__ __forceinline__ void gload_lds16(const void* g, void* l) {
    __builtin_amdgcn_global_load_lds(
        (const __attribute__((address_space(1))) void*)g,
        (__attribute__((address_space(3))) void*)l,
        16, 0, 0);
}

// ---- fp32 -> bf16 conversion for the three live inputs -------------------
__global__ __launch_bounds__(256)
void convert3_kernel(const float4* __restrict__ s0, const float4* __restrict__ s1,
                     const float4* __restrict__ s2,
                     ushort4* __restrict__ d0, ushort4* __restrict__ d1,
                     ushort4* __restrict__ d2, int nchunk) {
    int c = blockIdx.x * 256 + threadIdx.x;
    if (c >= nchunk) return;
    float4 v;
    ushort4 o;
    v = s0[c]; o.x = f2bf(v.x); o.y = f2bf(v.y); o.z = f2bf(v.z); o.w = f2bf(v.w); d0[c] = o;
    v = s1[c]; o.x = f2bf(v.x); o.y = f2bf(v.y); o.z = f2bf(v.z); o.w = f2bf(v.w); d1[c] = o;
    v = s2[c]; o.x = f2bf(v.x); o.y = f2bf(v.y); o.z = f2bf(v.z); o.w = f2bf(v.w); d2[c] = o;
}

// ---- per-row diagonals in full fp32 ---------------------------------------
__global__ __launch_bounds__(256)
void diag_kernel(const float4* __restrict__ art, const float4* __restrict__ tart,
                 const float4* __restrict__ gen,
                 float* __restrict__ diagA, float* __restrict__ diagG) {
    int row = blockIdx.x;
    int t = threadIdx.x;                      // 0..255, exactly D/4 chunks
    const float4* a  = art  + (size_t)row * (DDIM / 4);
    const float4* ta = tart + (size_t)row * (DDIM / 4);
    const float4* g  = gen  + (size_t)row * (DDIM / 4);
    float4 va = a[t], vt = ta[t], vg = g[t];
    float pa = va.x * vt.x + va.y * vt.y + va.z * vt.z + va.w * vt.w;
    float pg = vg.x * vg.x + vg.y * vg.y + vg.z * vg.z + vg.w * vg.w;
    for (int off = 32; off > 0; off >>= 1) {
        pa += __shfl_down(pa, off, 64);
        pg += __shfl_down(pg, off, 64);
    }
    __shared__ float sA[4], sG[4];
    int w = t >> 6, lane = t & 63;
    if (lane == 0) { sA[w] = pa; sG[w] = pg; }
    __syncthreads();
    if (t == 0) {
        diagA[row] = sA[0] + sA[1] + sA[2] + sA[3];
        diagG[row] = sG[0] + sG[1] + sG[2] + sG[3];
    }
}

// ---- fused GEMM + hinge + masked reduction --------------------------------
// 128x128 tile, BK=64, 4 waves (2x2), each wave: 64x64 out = 4x4 frags of 16x16.
__global__ __launch_bounds__(256)
void hinge_gemm_kernel(const unsigned short* __restrict__ A0,
                       const unsigned short* __restrict__ B0,
                       const float* __restrict__ diag0, float scale0,
                       const unsigned short* __restrict__ A1,
                       const unsigned short* __restrict__ B1,
                       const float* __restrict__ diag1, float scale1,
                       float* __restrict__ out) {
    const unsigned short* A;
    const unsigned short* B;
    const float* diag;
    float scale;
    if (blockIdx.z == 0) { A = A0; B = B0; diag = diag0; scale = scale0; }
    else                 { A = A1; B = B1; diag = diag1; scale = scale1; }

    __shared__ unsigned short sA[128 * 64];
    __shared__ unsigned short sB[128 * 64];

    const int tid = threadIdx.x;
    const int w = tid >> 6;
    const int lane = tid & 63;
    const int tr = blockIdx.x >> 5;   // 32x32 tiles
    const int tc = blockIdx.x & 31;
    const int waveRow = w >> 1, waveCol = w & 1;

    const unsigned short* Ablk = A + (size_t)tr * 128 * DDIM;
    const unsigned short* Bblk = B + (size_t)tc * 128 * DDIM;

    f32x4 acc[4][4];
#pragma unroll
    for (int m = 0; m < 4; ++m)
#pragma unroll
        for (int n = 0; n < 4; ++n)
            acc[m][n] = (f32x4){0.f, 0.f, 0.f, 0.f};

    for (int kt = 0; kt < DDIM; kt += 64) {
        __syncthreads();              // previous compute done before overwrite
#pragma unroll
        for (int i = 0; i < 4; ++i) {
            const int q = i * 256 + w * 64 + lane;   // 16B chunk id, 0..1023
            const int row = q >> 3, c16 = q & 7;
            gload_lds16(Ablk + row * DDIM + kt + c16 * 8, &sA[(i * 256 + w * 64) * 8]);
            gload_lds16(Bblk + row * DDIM + kt + c16 * 8, &sB[(i * 256 + w * 64) * 8]);
        }
        __syncthreads();              // drains vmcnt(0): staging complete
#pragma unroll
        for (int kk = 0; kk < 64; kk += 32) {
            bf16x8 af[4], bfr[4];
#pragma unroll
            for (int m = 0; m < 4; ++m) {
                const int r = waveRow * 64 + m * 16 + (lane & 15);
                af[m] = *(const bf16x8*)&sA[r * 64 + kk + (lane >> 4) * 8];
            }
#pragma unroll
            for (int n = 0; n < 4; ++n) {
                const int r = waveCol * 64 + n * 16 + (lane & 15);
                bfr[n] = *(const bf16x8*)&sB[r * 64 + kk + (lane >> 4) * 8];
            }
#pragma unroll
            for (int m = 0; m < 4; ++m)
#pragma unroll
                for (int n = 0; n < 4; ++n)
                    acc[m][n] = __builtin_amdgcn_mfma_f32_16x16x32_bf16(
                        af[m], bfr[n], acc[m][n], 0, 0, 0);
        }
    }

    // epilogue: hinge + diagonal mask + reduction
    // C/D layout (verified m89): col = lane&15, row = (lane>>4)*4 + reg
    const int rowBase = tr * 128 + waveRow * 64 + ((lane >> 4) << 2);
    const int colBase = tc * 128 + waveCol * 64 + (lane & 15);
    float lsum = 0.0f;
#pragma unroll
    for (int n = 0; n < 4; ++n) {
        const int gcol = colBase + n * 16;
        const float dc = MARGIN - diag[gcol];
#pragma unroll
        for (int m = 0; m < 4; ++m) {
            const int grow0 = rowBase + m * 16;
#pragma unroll
            for (int r = 0; r < 4; ++r) {
                float v = acc[m][n][r] + dc;
                v = fmaxf(v, 0.0f);
                if (grow0 + r == gcol) v = 0.0f;   // zero the diagonal
                lsum += v;
            }
        }
    }
    for (int off = 32; off > 0; off >>= 1) lsum += __shfl_down(lsum, off, 64);

    __shared__ float wsums[4];
    if (lane == 0) wsums[w] = lsum;
    __syncthreads();
    if (tid == 0)
        atomicAdd(out, scale * (wsums[0] + wsums[1] + wsums[2] + wsums[3]));
}

extern "C" void kernel_launch(void* const* d_in, const int* in_sizes, int n_in,
                              void* d_out, int out_size, void* d_ws, size_t ws_size,
                              hipStream_t stream) {
    // setup_inputs order: vgg(0) artist(1) genre(2) target_vgg(3) target_art(4) target_gen(5)
    const float* artist = (const float*)d_in[1];
    const float* genre  = (const float*)d_in[2];
    const float* tart   = (const float*)d_in[4];

    char* ws = (char*)d_ws;
    const size_t NE = (size_t)NROW * DDIM;
    unsigned short* artBf  = (unsigned short*)(ws);
    unsigned short* tartBf = (unsigned short*)(ws + NE * 2);
    unsigned short* genBf  = (unsigned short*)(ws + NE * 4);
    float* diagA = (float*)(ws + NE * 6);
    float* diagG = (float*)(ws + NE * 6 + NROW * 4);

    hipMemsetAsync(d_out, 0, sizeof(float), stream);

    const int nchunk = (int)(NE / 4);
    convert3_kernel<<<nchunk / 256, 256, 0, stream>>>(
        (const float4*)artist, (const float4*)tart, (const float4*)genre,
        (ushort4*)artBf, (ushort4*)tartBf, (ushort4*)genBf, nchunk);

    diag_kernel<<<NROW, 256, 0, stream>>>(
        (const float4*)artist, (const float4*)tart, (const float4*)genre,
        diagA, diagG);

    dim3 grid(1024, 1, 2);
    hinge_gemm_kernel<<<grid, 256, 0, stream>>>(
        artBf, tartBf, diagA, 2.0f,
        genBf, genBf, diagG, 1.0f,
        (float*)d_out);
}

// Round 2
// 104.348 us; speedup vs baseline: 1.2503x; 1.2503x over previous
//
#include <hip/hip_runtime.h>

// PairwiseRankingLoss: out = 2*sum(cost_a) + sum(cost_g)
//   cost_x[i,j] = relu(score_x[i,j] + 0.2 - diag_x[j]) * (i != j)
//   score_a = artist @ target_art^T ; score_g = genre @ genre^T (symmetric!)
// N=4096, D=1024. fp32 in; bf16 MFMA GEMM (2% rel threshold).
// Round 2: ring-3 counted-vmcnt pipeline (no vmcnt(0) drain in main loop),
//          genre upper-triangle symmetry, LDS source-swizzle, no atomics.

#define NROW 4096
#define DDIM 1024
#define MARGIN 0.2f
#define NT 32              // 4096 / 128 tiles per dim
#define NSLICE 32          // DDIM / 32
#define NBLK_ART 1024      // 32*32 artist tiles
#define NBLK_GEN 528       // upper triangle incl. diagonal
#define NBLK (NBLK_ART + NBLK_GEN)

typedef __bf16 bf16x8 __attribute__((ext_vector_type(8)));
typedef float f32x4 __attribute__((ext_vector_type(4)));

__device__ __forceinline__ unsigned short f2bf(float f) {
    unsigned int u = __builtin_bit_cast(unsigned int, f);
    u += 0x7fffu + ((u >> 16) & 1u);   // RNE
    return (unsigned short)(u >> 16);
}

__device__ __forceinline__ void gload_lds16(const void* g, void* l) {
    __builtin_amdgcn_global_load_lds(
        (const __attribute__((address_space(1))) void*)g,
        (__attribute__((address_space(3))) void*)l,
        16, 0, 0);
}

// ---- fused fp32->bf16 convert + per-row diagonals --------------------------
__global__ __launch_bounds__(256)
void prep_kernel(const float4* __restrict__ art, const float4* __restrict__ tart,
                 const float4* __restrict__ gen,
                 ushort4* __restrict__ artB, ushort4* __restrict__ tartB,
                 ushort4* __restrict__ genB,
                 float* __restrict__ diagA, float* __restrict__ diagG) {
    const int row = blockIdx.x;
    const int t = threadIdx.x;                  // 256 = DDIM/4 chunks
    const size_t idx = (size_t)row * (DDIM / 4) + t;
    float4 va = art[idx], vt = tart[idx], vg = gen[idx];
    ushort4 o;
    o.x = f2bf(va.x); o.y = f2bf(va.y); o.z = f2bf(va.z); o.w = f2bf(va.w); artB[idx] = o;
    o.x = f2bf(vt.x); o.y = f2bf(vt.y); o.z = f2bf(vt.z); o.w = f2bf(vt.w); tartB[idx] = o;
    o.x = f2bf(vg.x); o.y = f2bf(vg.y); o.z = f2bf(vg.z); o.w = f2bf(vg.w); genB[idx] = o;
    float pa = va.x * vt.x + va.y * vt.y + va.z * vt.z + va.w * vt.w;
    float pg = vg.x * vg.x + vg.y * vg.y + vg.z * vg.z + vg.w * vg.w;
    for (int off = 32; off > 0; off >>= 1) {
        pa += __shfl_down(pa, off, 64);
        pg += __shfl_down(pg, off, 64);
    }
    __shared__ float sA[4], sG[4];
    if ((t & 63) == 0) { sA[t >> 6] = pa; sG[t >> 6] = pg; }
    __syncthreads();
    if (t == 0) {
        diagA[row] = sA[0] + sA[1] + sA[2] + sA[3];
        diagG[row] = sG[0] + sG[1] + sG[2] + sG[3];
    }
}

// ---- fused GEMM + hinge + reduction ----------------------------------------
// 128x128 tile, 4 waves (2x2), per wave 64x64 = 4x4 frags of 16x16x32.
// LDS: ring of 3 K-slices (BK=32): 3 * (128x32 A + 128x32 B) bf16 = 48 KiB.
// Swizzle: 16B slot index ^= (row&3) applied on global SOURCE and on LDS READ.

__shared__ __align__(16) unsigned short sA[3][128 * 32];
__shared__ __align__(16) unsigned short sB[3][128 * 32];

__device__ __forceinline__
void stage_slice(const unsigned short* __restrict__ Ablk,
                 const unsigned short* __restrict__ Bblk,
                 int kt, int ring, int w, int lane) {
#pragma unroll
    for (int i = 0; i < 2; ++i) {
        const int q = i * 256 + w * 64 + lane;      // 16B chunk id, 0..511
        const int row = q >> 2;
        const int slot = q & 3;
        const int gcol = kt + ((slot ^ (row & 3)) << 3);   // inverse-swizzled source
        gload_lds16(Ablk + (size_t)row * DDIM + gcol, &sA[ring][(size_t)(i * 256 + w * 64) * 8]);
        gload_lds16(Bblk + (size_t)row * DDIM + gcol, &sB[ring][(size_t)(i * 256 + w * 64) * 8]);
    }
}

template <int VM>
__device__ __forceinline__
void kstep(int s, const unsigned short* __restrict__ Ablk,
           const unsigned short* __restrict__ Bblk,
           f32x4 acc[4][4], int w, int lane, int waveRow, int waveCol) {
    const int kt_pre = (s + 2) * 32;
    if (kt_pre < DDIM) stage_slice(Ablk, Bblk, kt_pre, (s + 2) % 3, w, lane);

    // wait: slice s fully landed (up to 2 newer slices = 8 loads stay in flight)
    if (VM == 8)      asm volatile("s_waitcnt vmcnt(8)" ::: "memory");
    else if (VM == 4) asm volatile("s_waitcnt vmcnt(4)" ::: "memory");
    else              asm volatile("s_waitcnt vmcnt(0)" ::: "memory");
    __builtin_amdgcn_s_barrier();                 // all waves' slice-s loads landed
    __builtin_amdgcn_sched_barrier(0);

    const unsigned short* a = sA[s % 3];
    const unsigned short* b = sB[s % 3];
    const int kgrp = lane >> 4;
    bf16x8 af[4], bfr[4];
#pragma unroll
    for (int m = 0; m < 4; ++m) {
        const int r = waveRow * 64 + m * 16 + (lane & 15);
        af[m] = *(const bf16x8*)&a[r * 32 + ((kgrp ^ (r & 3)) << 3)];
    }
#pragma unroll
    for (int n = 0; n < 4; ++n) {
        const int r = waveCol * 64 + n * 16 + (lane & 15);
        bfr[n] = *(const bf16x8*)&b[r * 32 + ((kgrp ^ (r & 3)) << 3)];
    }
    asm volatile("s_waitcnt lgkmcnt(0)" ::: "memory");   // reads done...
    __builtin_amdgcn_s_barrier();                        // ...in ALL waves: slot s reusable
    __builtin_amdgcn_sched_barrier(0);

    __builtin_amdgcn_s_setprio(1);
#pragma unroll
    for (int m = 0; m < 4; ++m)
#pragma unroll
        for (int n = 0; n < 4; ++n)
            acc[m][n] = __builtin_amdgcn_mfma_f32_16x16x32_bf16(af[m], bfr[n], acc[m][n], 0, 0, 0);
    __builtin_amdgcn_s_setprio(0);
}

__global__ __launch_bounds__(256)
void hinge_gemm_kernel(const unsigned short* __restrict__ artB,
                       const unsigned short* __restrict__ tartB,
                       const unsigned short* __restrict__ genB,
                       const float* __restrict__ diagA,
                       const float* __restrict__ diagG,
                       float* __restrict__ partials) {
    const int bid = blockIdx.x;
    const unsigned short* A;
    const unsigned short* B;
    const float* dg;
    int tr, tc, mode;      // mode 0: single hinge + diag mask; 1: dual hinge (sym)
    float scale;
    if (bid < NBLK_ART) {
        A = artB; B = tartB; dg = diagA; scale = 2.0f;
        tr = bid >> 5; tc = bid & 31; mode = 0;
    } else {
        int t = bid - NBLK_ART;
        int r = 0;
        while (t >= NT - r) { t -= NT - r; ++r; }
        tr = r; tc = r + t;
        A = genB; B = genB; dg = diagG; scale = 1.0f;
        mode = (tr == tc) ? 0 : 1;
    }

    const int tid = threadIdx.x;
    const int w = tid >> 6;
    const int lane = tid & 63;
    const int waveRow = w >> 1, waveCol = w & 1;

    const unsigned short* Ablk = A + (size_t)tr * 128 * DDIM;
    const unsigned short* Bblk = B + (size_t)tc * 128 * DDIM;

    f32x4 acc[4][4];
#pragma unroll
    for (int m = 0; m < 4; ++m)
#pragma unroll
        for (int n = 0; n < 4; ++n)
            acc[m][n] = (f32x4){0.f, 0.f, 0.f, 0.f};

    // prologue: slices 0,1 in flight
    stage_slice(Ablk, Bblk, 0, 0, w, lane);
    stage_slice(Ablk, Bblk, 32, 1, w, lane);

    for (int s = 0; s < NSLICE - 2; ++s)
        kstep<8>(s, Ablk, Bblk, acc, w, lane, waveRow, waveCol);
    kstep<4>(NSLICE - 2, Ablk, Bblk, acc, w, lane, waveRow, waveCol);
    kstep<0>(NSLICE - 1, Ablk, Bblk, acc, w, lane, waveRow, waveCol);

    // epilogue: hinge + reduction.  C/D layout: col=lane&15, row=(lane>>4)*4+reg
    const int rowBase = tr * 128 + waveRow * 64 + ((lane >> 4) << 2);
    const int colBase = tc * 128 + waveCol * 64 + (lane & 15);
    float lsum = 0.0f;
    if (mode == 0) {
#pragma unroll
        for (int n = 0; n < 4; ++n) {
            const int gcol = colBase + n * 16;
            const float dc = MARGIN - dg[gcol];
#pragma unroll
            for (int m = 0; m < 4; ++m) {
                const int grow0 = rowBase + m * 16;
#pragma unroll
                for (int r = 0; r < 4; ++r) {
                    float v = fmaxf(acc[m][n][r] + dc, 0.0f);
                    if (grow0 + r == gcol) v = 0.0f;
                    lsum += v;
                }
            }
        }
    } else {
        // symmetric off-diagonal genre tile: each score v = g[i,j] = g[j,i]
        // contributes relu(v + c_j) [this tile] + relu(v + c_i) [mirror tile]
        float drow[16];
#pragma unroll
        for (int m = 0; m < 4; ++m)
#pragma unroll
            for (int r = 0; r < 4; ++r)
                drow[m * 4 + r] = MARGIN - dg[rowBase + m * 16 + r];
#pragma unroll
        for (int n = 0; n < 4; ++n) {
            const int gcol = colBase + n * 16;
            const float dc = MARGIN - dg[gcol];
#pragma unroll
            for (int m = 0; m < 4; ++m)
#pragma unroll
                for (int r = 0; r < 4; ++r) {
                    const float v = acc[m][n][r];
                    lsum += fmaxf(v + dc, 0.0f) + fmaxf(v + drow[m * 4 + r], 0.0f);
                }
        }
    }
    for (int off = 32; off > 0; off >>= 1) lsum += __shfl_down(lsum, off, 64);

    __shared__ float wsums[4];
    if (lane == 0) wsums[w] = lsum;
    __syncthreads();
    if (tid == 0)
        partials[bid] = scale * (wsums[0] + wsums[1] + wsums[2] + wsums[3]);
}

// ---- final reduction --------------------------------------------------------
__global__ __launch_bounds__(256)
void reduce_kernel(const float* __restrict__ p, float* __restrict__ out) {
    const int t = threadIdx.x;
    float s = 0.f;
    for (int i = t; i < NBLK; i += 256) s += p[i];
    for (int off = 32; off > 0; off >>= 1) s += __shfl_down(s, off, 64);
    __shared__ float ws[4];
    if ((t & 63) == 0) ws[t >> 6] = s;
    __syncthreads();
    if (t == 0) out[0] = ws[0] + ws[1] + ws[2] + ws[3];
}

extern "C" void kernel_launch(void* const* d_in, const int* in_sizes, int n_in,
                              void* d_out, int out_size, void* d_ws, size_t ws_size,
                              hipStream_t stream) {
    // inputs: vgg(0) artist(1) genre(2) target_vgg(3) target_art(4) target_gen(5)
    const float* artist = (const float*)d_in[1];
    const float* genre  = (const float*)d_in[2];
    const float* tart   = (const float*)d_in[4];

    char* ws = (char*)d_ws;
    const size_t NE = (size_t)NROW * DDIM;
    unsigned short* artBf  = (unsigned short*)(ws);
    unsigned short* tartBf = (unsigned short*)(ws + NE * 2);
    unsigned short* genBf  = (unsigned short*)(ws + NE * 4);
    float* diagA    = (float*)(ws + NE * 6);
    float* diagG    = (float*)(ws + NE * 6 + NROW * 4);
    float* partials = (float*)(ws + NE * 6 + NROW * 8);

    prep_kernel<<<NROW, 256, 0, stream>>>(
        (const float4*)artist, (const float4*)tart, (const float4*)genre,
        (ushort4*)artBf, (ushort4*)tartBf, (ushort4*)genBf, diagA, diagG);

    hinge_gemm_kernel<<<NBLK, 256, 0, stream>>>(
        artBf, tartBf, genBf, diagA, diagG, partials);

    reduce_kernel<<<1, 256, 0, stream>>>(partials, (float*)d_out);
}

// Round 3
// 77.979 us; speedup vs baseline: 1.6731x; 1.3382x over previous
//
#include <hip/hip_runtime.h>

// PairwiseRankingLoss: out = 2*sum(cost_a) + sum(cost_g)
//   cost_x[i,j] = relu(score_x[i,j] + 0.2 - diag_x[j]) * (i != j)
//   score_a = artist @ target_art^T ; score_g = genre @ genre^T (symmetric)
// N=4096, D=1024. fp32 in; bf16 MFMA (2% rel threshold).
// Round 3: 256x256 8-wave 4-phase-per-K-tile schedule (T2+T3+T4+T5),
//          counted vmcnt, XOR-swizzled LDS, genre triangle symmetry.

#define NROW 4096
#define DDIM 1024
#define MARGIN 0.2f
#define NT 16               // 4096 / 256 tiles per dim
#define NKT 16              // 1024 / 64 K-tiles
#define NBLK_ART 256        // 16*16 artist tiles
#define NBLK_GEN 136        // genre upper triangle incl. diagonal
#define NBLK (NBLK_ART + NBLK_GEN)   // 392 (divisible by 8)

typedef __bf16 bf16x8 __attribute__((ext_vector_type(8)));
typedef float f32x4 __attribute__((ext_vector_type(4)));

__device__ __forceinline__ unsigned short f2bf(float f) {
    unsigned int u = __builtin_bit_cast(unsigned int, f);
    u += 0x7fffu + ((u >> 16) & 1u);   // RNE
    return (unsigned short)(u >> 16);
}

__device__ __forceinline__ void gload_lds16(const void* g, void* l) {
    __builtin_amdgcn_global_load_lds(
        (const __attribute__((address_space(1))) void*)g,
        (__attribute__((address_space(3))) void*)l,
        16, 0, 0);
}

// ---- fused fp32->bf16 convert + per-row diagonals --------------------------
__global__ __launch_bounds__(256)
void prep_kernel(const float4* __restrict__ art, const float4* __restrict__ tart,
                 const float4* __restrict__ gen,
                 ushort4* __restrict__ artB, ushort4* __restrict__ tartB,
                 ushort4* __restrict__ genB,
                 float* __restrict__ diagA, float* __restrict__ diagG) {
    const int row = blockIdx.x;
    const int t = threadIdx.x;                  // 256 = DDIM/4 chunks
    const size_t idx = (size_t)row * (DDIM / 4) + t;
    float4 va = art[idx], vt = tart[idx], vg = gen[idx];
    ushort4 o;
    o.x = f2bf(va.x); o.y = f2bf(va.y); o.z = f2bf(va.z); o.w = f2bf(va.w); artB[idx] = o;
    o.x = f2bf(vt.x); o.y = f2bf(vt.y); o.z = f2bf(vt.z); o.w = f2bf(vt.w); tartB[idx] = o;
    o.x = f2bf(vg.x); o.y = f2bf(vg.y); o.z = f2bf(vg.z); o.w = f2bf(vg.w); genB[idx] = o;
    float pa = va.x * vt.x + va.y * vt.y + va.z * vt.z + va.w * vt.w;
    float pg = vg.x * vg.x + vg.y * vg.y + vg.z * vg.z + vg.w * vg.w;
    for (int off = 32; off > 0; off >>= 1) {
        pa += __shfl_down(pa, off, 64);
        pg += __shfl_down(pg, off, 64);
    }
    __shared__ float sA[4], sG[4];
    if ((t & 63) == 0) { sA[t >> 6] = pa; sG[t >> 6] = pg; }
    __syncthreads();
    if (t == 0) {
        diagA[row] = sA[0] + sA[1] + sA[2] + sA[3];
        diagG[row] = sG[0] + sG[1] + sG[2] + sG[3];
    }
}

// ---- GEMM tile helpers ------------------------------------------------------
// LDS layout (ushort elems, 65536 total = 128 KiB):
//   A buf b: [b*16384, +16384)   B buf b: [32768 + b*16384, +16384)
// Row r (0..255) of a tile = 64 bf16 = 8 slots of 16B.
// Swizzle: LDS (r, slot) holds global (r, slot ^ (r&7))  [involution].

// Stage one half-tile h: K-tile t = h>>2, arr = h&1 (0=A,1=B), half = (h>>1)&1.
// 512 threads x 2 x 16B = 128 rows x 64 cols. LDS dest linear (gload_lds rule),
// source column pre-swizzled.
__device__ __forceinline__
void stage_half(int h, const unsigned short* __restrict__ Ablk,
                const unsigned short* __restrict__ Bblk,
                unsigned short* sh, int tid) {
    const int t = h >> 2;
    const int arr = h & 1;
    const int half = (h >> 1) & 1;
    const int kt = t << 6;
    const unsigned short* src = arr ? Bblk : Ablk;
    unsigned short* dst = sh + (arr ? 32768 : 0) + (t & 1) * 16384 + half * 8192;
#pragma unroll
    for (int i = 0; i < 2; ++i) {
        const int q = i * 512 + tid;                 // 16B chunk 0..1023
        const int r = half * 128 + (q >> 3);
        const int gcol = ((q & 7) ^ (r & 7)) << 3;   // inverse-swizzled source col
        gload_lds16(src + (size_t)r * DDIM + kt + gcol, dst + q * 8);
    }
}

__device__ __forceinline__ bf16x8 lds_frag(const unsigned short* base, int r, int kh, int lane) {
    const int slot = ((kh << 2) + (lane >> 4)) ^ (r & 7);
    return *(const bf16x8*)&base[r * 64 + slot * 8];
}

template <int MH>
__device__ __forceinline__
void loadA(bf16x8 aF[2][4], const unsigned short* ldsA, int waveM, int lane) {
#pragma unroll
    for (int kh = 0; kh < 2; ++kh)
#pragma unroll
        for (int m = 0; m < 4; ++m) {
            const int r = waveM * 128 + (MH * 4 + m) * 16 + (lane & 15);
            aF[kh][m] = lds_frag(ldsA, r, kh, lane);
        }
}

template <int NH>
__device__ __forceinline__
void loadB(bf16x8 bFn[2][2], const unsigned short* ldsB, int waveN, int lane) {
#pragma unroll
    for (int kh = 0; kh < 2; ++kh)
#pragma unroll
        for (int n = 0; n < 2; ++n) {
            const int r = waveN * 64 + (NH * 2 + n) * 16 + (lane & 15);
            bFn[kh][n] = lds_frag(ldsB, r, kh, lane);
        }
}

template <int MH, int NH>
__device__ __forceinline__
void mfmaQuad(f32x4 acc[8][4], const bf16x8 aF[2][4], const bf16x8 bFn[2][2]) {
#pragma unroll
    for (int kh = 0; kh < 2; ++kh)
#pragma unroll
        for (int m = 0; m < 4; ++m)
#pragma unroll
            for (int n = 0; n < 2; ++n)
                acc[MH * 4 + m][NH * 2 + n] = __builtin_amdgcn_mfma_f32_16x16x32_bf16(
                    aF[kh][m], bFn[kh][n], acc[MH * 4 + m][NH * 2 + n], 0, 0, 0);
}

// ---- fused 256x256 GEMM + hinge + reduction ---------------------------------
__global__ __launch_bounds__(512, 2)
void hinge_gemm_kernel(const unsigned short* __restrict__ artB,
                       const unsigned short* __restrict__ tartB,
                       const unsigned short* __restrict__ genB,
                       const float* __restrict__ diagA,
                       const float* __restrict__ diagG,
                       float* __restrict__ partials) {
    __shared__ unsigned short sh[65536];   // 128 KiB

    // bijective XCD swizzle: 392 = 8 * 49
    const int bid = ((int)blockIdx.x & 7) * 49 + ((int)blockIdx.x >> 3);

    const unsigned short* A;
    const unsigned short* B;
    const float* dg;
    int tr, tc, mode;          // mode 0: single hinge + diag mask; 1: dual hinge
    float scale;
    if (bid < NBLK_ART) {
        A = artB; B = tartB; dg = diagA; scale = 2.0f;
        tr = bid >> 4; tc = bid & 15; mode = 0;
    } else {
        int u = bid - NBLK_ART;
        int r = 0;
        while (u >= NT - r) { u -= NT - r; ++r; }
        tr = r; tc = r + u;
        A = genB; B = genB; dg = diagG; scale = 1.0f;
        mode = (tr == tc) ? 0 : 1;
    }

    const int tid = threadIdx.x;
    const int w = tid >> 6;
    const int lane = tid & 63;
    const int waveM = w >> 2;        // 2 wave-rows
    const int waveN = w & 3;         // 4 wave-cols

    const unsigned short* Ablk = A + (size_t)tr * 256 * DDIM;
    const unsigned short* Bblk = B + (size_t)tc * 256 * DDIM;

    f32x4 acc[8][4];
#pragma unroll
    for (int m = 0; m < 8; ++m)
#pragma unroll
        for (int n = 0; n < 4; ++n)
            acc[m][n] = (f32x4){0.f, 0.f, 0.f, 0.f};

    bf16x8 aF[2][4];
    bf16x8 bF[2][2][2];

    // prologue: K-tile 0's 4 half-tiles in flight (8 loads/thread)
    stage_half(0, Ablk, Bblk, sh, tid);
    stage_half(1, Ablk, Bblk, sh, tid);
    stage_half(2, Ablk, Bblk, sh, tid);
    stage_half(3, Ablk, Bblk, sh, tid);

#pragma unroll 1
    for (int t = 0; t < NKT; ++t) {
        const unsigned short* ldsA = sh + (t & 1) * 16384;
        const unsigned short* ldsB = sh + 32768 + (t & 1) * 16384;
        const bool pre = (t + 1 < NKT);
        const int hb = (t + 1) << 2;

        // ---- phase 0 (quadrant mh=0,nh=0): buffer-ready boundary ----
        if (pre) stage_half(hb + 0, Ablk, Bblk, sh, tid);
        if (pre) { asm volatile("s_waitcnt vmcnt(2)" ::: "memory"); }
        else     { asm volatile("s_waitcnt vmcnt(0)" ::: "memory"); }
        __builtin_amdgcn_s_barrier();            // ALL waves' tile-t loads landed
        __builtin_amdgcn_sched_barrier(0);
        loadA<0>(aF, ldsA, waveM, lane);
        loadB<0>(bF[0], ldsB, waveN, lane);
        asm volatile("s_waitcnt lgkmcnt(0)" ::: "memory");
        __builtin_amdgcn_sched_barrier(0);
        __builtin_amdgcn_s_setprio(1);
        mfmaQuad<0, 0>(acc, aF, bF[0]);
        __builtin_amdgcn_s_setprio(0);
        __builtin_amdgcn_s_barrier();

        // ---- phase 1 (mh=0,nh=1) ----
        loadB<1>(bF[1], ldsB, waveN, lane);
        if (pre) stage_half(hb + 1, Ablk, Bblk, sh, tid);
        __builtin_amdgcn_s_barrier();
        asm volatile("s_waitcnt lgkmcnt(0)" ::: "memory");
        __builtin_amdgcn_sched_barrier(0);
        __builtin_amdgcn_s_setprio(1);
        mfmaQuad<0, 1>(acc, aF, bF[1]);
        __builtin_amdgcn_s_setprio(0);
        __builtin_amdgcn_s_barrier();

        // ---- phase 2 (mh=1,nh=0) ----
        loadA<1>(aF, ldsA, waveM, lane);
        if (pre) stage_half(hb + 2, Ablk, Bblk, sh, tid);
        __builtin_amdgcn_s_barrier();
        asm volatile("s_waitcnt lgkmcnt(0)" ::: "memory");
        __builtin_amdgcn_sched_barrier(0);
        __builtin_amdgcn_s_setprio(1);
        mfmaQuad<1, 0>(acc, aF, bF[0]);
        __builtin_amdgcn_s_setprio(0);
        __builtin_amdgcn_s_barrier();

        // ---- phase 3 (mh=1,nh=1) ----
        if (pre) stage_half(hb + 3, Ablk, Bblk, sh, tid);
        __builtin_amdgcn_s_barrier();
        __builtin_amdgcn_s_setprio(1);
        mfmaQuad<1, 1>(acc, aF, bF[1]);
        __builtin_amdgcn_s_setprio(0);
        __builtin_amdgcn_s_barrier();
    }

    // ---- epilogue: hinge + reduction ----
    // C/D layout: col = lane&15, row = (lane>>4)*4 + reg
    const int rowBase = tr * 256 + waveM * 128 + ((lane >> 4) << 2);
    const int colBase = tc * 256 + waveN * 64 + (lane & 15);
    float lsum = 0.0f;
    if (mode == 0) {
#pragma unroll
        for (int nf = 0; nf < 4; ++nf) {
            const int gcol = colBase + nf * 16;
            const float dc = MARGIN - dg[gcol];
#pragma unroll
            for (int mf = 0; mf < 8; ++mf) {
                const int grow0 = rowBase + mf * 16;
#pragma unroll
                for (int r = 0; r < 4; ++r) {
                    float v = fmaxf(acc[mf][nf][r] + dc, 0.0f);
                    if (grow0 + r == gcol) v = 0.0f;
                    lsum += v;
                }
            }
        }
    } else {
        // strictly-above-diagonal genre tile: v = g[i,j] = g[j,i] contributes
        // relu(v + c_j) [this tile] + relu(v + c_i) [mirror tile]
        float drow[8][4];
#pragma unroll
        for (int mf = 0; mf < 8; ++mf)
#pragma unroll
            for (int r = 0; r < 4; ++r)
                drow[mf][r] = MARGIN - dg[rowBase + mf * 16 + r];
#pragma unroll
        for (int nf = 0; nf < 4; ++nf) {
            const float dc = MARGIN - dg[colBase + nf * 16];
#pragma unroll
            for (int mf = 0; mf < 8; ++mf)
#pragma unroll
                for (int r = 0; r < 4; ++r) {
                    const float v = acc[mf][nf][r];
                    lsum += fmaxf(v + dc, 0.0f) + fmaxf(v + drow[mf][r], 0.0f);
                }
        }
    }
    for (int off = 32; off > 0; off >>= 1) lsum += __shfl_down(lsum, off, 64);

    __syncthreads();                     // LDS reuse for cross-wave reduce
    float* ws = (float*)sh;
    if (lane == 0) ws[w] = lsum;
    __syncthreads();
    if (tid == 0) {
        float s = 0.f;
#pragma unroll
        for (int i = 0; i < 8; ++i) s += ws[i];
        partials[blockIdx.x] = scale * s;
    }
}

// ---- final reduction --------------------------------------------------------
__global__ __launch_bounds__(256)
void reduce_kernel(const float* __restrict__ p, float* __restrict__ out) {
    const int t = threadIdx.x;
    float s = 0.f;
    for (int i = t; i < NBLK; i += 256) s += p[i];
    for (int off = 32; off > 0; off >>= 1) s += __shfl_down(s, off, 64);
    __shared__ float ws[4];
    if ((t & 63) == 0) ws[t >> 6] = s;
    __syncthreads();
    if (t == 0) out[0] = ws[0] + ws[1] + ws[2] + ws[3];
}

extern "C" void kernel_launch(void* const* d_in, const int* in_sizes, int n_in,
                              void* d_out, int out_size, void* d_ws, size_t ws_size,
                              hipStream_t stream) {
    // inputs: vgg(0) artist(1) genre(2) target_vgg(3) target_art(4) target_gen(5)
    const float* artist = (const float*)d_in[1];
    const float* genre  = (const float*)d_in[2];
    const float* tart   = (const float*)d_in[4];

    char* ws = (char*)d_ws;
    const size_t NE = (size_t)NROW * DDIM;
    unsigned short* artBf  = (unsigned short*)(ws);
    unsigned short* tartBf = (unsigned short*)(ws + NE * 2);
    unsigned short* genBf  = (unsigned short*)(ws + NE * 4);
    float* diagA    = (float*)(ws + NE * 6);
    float* diagG    = (float*)(ws + NE * 6 + NROW * 4);
    float* partials = (float*)(ws + NE * 6 + NROW * 8);

    prep_kernel<<<NROW, 256, 0, stream>>>(
        (const float4*)artist, (const float4*)tart, (const float4*)genre,
        (ushort4*)artBf, (ushort4*)tartBf, (ushort4*)genBf, diagA, diagG);

    hinge_gemm_kernel<<<NBLK, 512, 0, stream>>>(
        artBf, tartBf, genBf, diagA, diagG, partials);

    reduce_kernel<<<1, 256, 0, stream>>>(partials, (float*)d_out);
}